// Round 6
// baseline (681.721 us; speedup 1.0000x reference)
//
#include <hip/hip_runtime.h>

// GIN round 14: kill the grid-granularity tail. 782 blocks / 256 CUs = 3.05
// -> 14 CUs ran 4 blocks while 242 ran 3 (31% structural tail; explains the
// 26% time-avg occupancy). Tiles halved to 64 rows / 256 threads: grid 1563
// (~6.1/CU), ~7 resident blocks/CU -> hardware greedy scheduling balances.
// Gather restored to 8-deep (R13's 16-deep was neutral-negative, VGPR flat).
// Same change in mfma_gemm (encoder + GEMM2). Everything else unchanged.
// MFMA bf16 GEMMs, bf16 h/m, bucketed CSR, folded BN, run-length pooling.

#define BN_EPS 1e-5f
#define CURS_STRIDE 16

typedef __attribute__((ext_vector_type(8))) short short8;
typedef __attribute__((ext_vector_type(4))) float f32x4;

// ---- bf16 helpers (rne) ----
__device__ __forceinline__ unsigned int pack_bf16x2(float a, float b) {
    unsigned int ua = __float_as_uint(a);
    unsigned int ub = __float_as_uint(b);
    ua = (ua + 0x7FFFu + ((ua >> 16) & 1u)) >> 16;
    ub = (ub + 0x7FFFu + ((ub >> 16) & 1u)) >> 16;
    return ua | (ub << 16);
}
__device__ __forceinline__ unsigned short bf16_1(float f) {
    unsigned int u = __float_as_uint(f);
    u = (u + 0x7FFFu + ((u >> 16) & 1u)) >> 16;
    return (unsigned short)u;
}
__device__ __forceinline__ float2 unpack_bf16x2(unsigned int u) {
    float2 r;
    r.x = __uint_as_float(u << 16);
    r.y = __uint_as_float(u & 0xFFFF0000u);
    return r;
}

template<bool BN>
__device__ __forceinline__ void acc_row8(float (&acc)[8], uint4 p,
                                         const float* sc, const float* sh) {
    unsigned int pp[4] = {p.x, p.y, p.z, p.w};
    #pragma unroll
    for (int t = 0; t < 4; t++) {
        float2 f = unpack_bf16x2(pp[t]);
        if (BN) {
            f.x = fmaxf(fmaf(f.x, sc[2 * t],     sh[2 * t]),     0.f);
            f.y = fmaxf(fmaf(f.y, sc[2 * t + 1], sh[2 * t + 1]), 0.f);
        }
        acc[2 * t]     += f.x;
        acc[2 * t + 1] += f.y;
    }
}

// ---------------------------------------------------------------------------
// Fused GIN conv stage 1: A[n] = t(hb[n]) + sum_{s in nbrs(n)} t(hb[s]),
// out = bf16(A @ W1 + b1), column stats of out -> s1. t = BN?relu(v*s+sh):v.
// Block: 256 thr / 4 waves; tile 64 rows x 64 cols; 8-deep gather.
template<bool BN>
__global__ __launch_bounds__(256)
void gin_gemm1(const int* __restrict__ rowp, const int* __restrict__ srcs,
               const unsigned int* __restrict__ hb,
               const float* __restrict__ bsum, const float* __restrict__ bsumsq,
               const float* __restrict__ gamma, const float* __restrict__ beta,
               float invN,
               const float* __restrict__ W, const float* __restrict__ bias,
               unsigned short* __restrict__ out,
               float* __restrict__ stat_sum, float* __restrict__ stat_sumsq,
               int N)
{
    constexpr int AS = 72, WS = 72, KH = 2;
    __shared__ short a_lds[64 * AS];
    __shared__ short wt_lds[64 * WS];
    __shared__ float ssf[128];
    __shared__ float red[512];

    const int tid = threadIdx.x;
    const int nb  = blockIdx.x * 64;
    const int l   = tid & 63;
    const int w   = tid >> 6;      // 0..3
    const int ln  = l & 15;
    const int q   = l >> 4;

    if (BN) {
        if (tid < 64) {
            float mu  = bsum[tid] * invN;
            float var = bsumsq[tid] * invN - mu * mu;
            float s   = gamma[tid] * rsqrtf(var + BN_EPS);
            ssf[tid]      = s;
            ssf[64 + tid] = beta[tid] - s * mu;
        }
        __syncthreads();
    }

    // stage W^T bf16
    for (int idx = tid; idx < 64 * 64; idx += 256) {
        int k = idx >> 6, n = idx & 63;
        wt_lds[n * WS + k] = (short)bf16_1(W[idx]);
    }

    // gather: 8 lanes/row, uint4 (8 bf16)/lane; 32 rows/pass, 2 passes
    const uint4* hb4 = (const uint4*)hb;
    const int cc = tid & 7;
    const int rl = tid >> 3;       // 0..31
    float sc[8], sh[8];
    if (BN) {
        #pragma unroll
        for (int j = 0; j < 8; j++) {
            sc[j] = ssf[cc * 8 + j];
            sh[j] = ssf[64 + cc * 8 + j];
        }
    }
    #pragma unroll
    for (int it = 0; it < 2; it++) {
        int rloc = it * 32 + rl;
        int n = nb + rloc;
        float acc[8] = {0.f, 0.f, 0.f, 0.f, 0.f, 0.f, 0.f, 0.f};
        if (n < N) {
            uint4 p = hb4[(size_t)n * 8 + cc];
            acc_row8<BN>(acc, p, sc, sh);
            int e = rowp[n], end = rowp[n + 1];
            // 8-deep: 8 independent gathers in flight for this row
            for (; e + 7 < end; e += 8) {
                int a0 = srcs[e],     a1 = srcs[e + 1];
                int a2 = srcs[e + 2], a3 = srcs[e + 3];
                int a4 = srcs[e + 4], a5 = srcs[e + 5];
                int a6 = srcs[e + 6], a7 = srcs[e + 7];
                uint4 p0 = hb4[(size_t)a0 * 8 + cc];
                uint4 p1 = hb4[(size_t)a1 * 8 + cc];
                uint4 p2 = hb4[(size_t)a2 * 8 + cc];
                uint4 p3 = hb4[(size_t)a3 * 8 + cc];
                uint4 p4 = hb4[(size_t)a4 * 8 + cc];
                uint4 p5 = hb4[(size_t)a5 * 8 + cc];
                uint4 p6 = hb4[(size_t)a6 * 8 + cc];
                uint4 p7 = hb4[(size_t)a7 * 8 + cc];
                acc_row8<BN>(acc, p0, sc, sh);
                acc_row8<BN>(acc, p1, sc, sh);
                acc_row8<BN>(acc, p2, sc, sh);
                acc_row8<BN>(acc, p3, sc, sh);
                acc_row8<BN>(acc, p4, sc, sh);
                acc_row8<BN>(acc, p5, sc, sh);
                acc_row8<BN>(acc, p6, sc, sh);
                acc_row8<BN>(acc, p7, sc, sh);
            }
            for (; e + 3 < end; e += 4) {
                int a0 = srcs[e], a1 = srcs[e + 1], a2 = srcs[e + 2], a3 = srcs[e + 3];
                uint4 p0 = hb4[(size_t)a0 * 8 + cc];
                uint4 p1 = hb4[(size_t)a1 * 8 + cc];
                uint4 p2 = hb4[(size_t)a2 * 8 + cc];
                uint4 p3 = hb4[(size_t)a3 * 8 + cc];
                acc_row8<BN>(acc, p0, sc, sh);
                acc_row8<BN>(acc, p1, sc, sh);
                acc_row8<BN>(acc, p2, sc, sh);
                acc_row8<BN>(acc, p3, sc, sh);
            }
            for (; e < end; e++) {
                uint4 pp = hb4[(size_t)srcs[e] * 8 + cc];
                acc_row8<BN>(acc, pp, sc, sh);
            }
        }
        uint4 o;
        o.x = pack_bf16x2(acc[0], acc[1]);
        o.y = pack_bf16x2(acc[2], acc[3]);
        o.z = pack_bf16x2(acc[4], acc[5]);
        o.w = pack_bf16x2(acc[6], acc[7]);
        *(uint4*)&a_lds[rloc * AS + cc * 8] = o;
    }
    __syncthreads();

    // fragments: one 16x64 row-tile per wave
    short8 afrag[KH], bfrag[4][KH];
    const int rw = w * 16;
    #pragma unroll
    for (int kh = 0; kh < KH; kh++)
        afrag[kh] = *(const short8*)&a_lds[(rw + ln) * AS + kh * 32 + q * 8];
    #pragma unroll
    for (int nt = 0; nt < 4; nt++)
        #pragma unroll
        for (int kh = 0; kh < KH; kh++)
            bfrag[nt][kh] = *(const short8*)&wt_lds[(nt * 16 + ln) * WS + kh * 32 + q * 8];

    f32x4 acc[4];
    #pragma unroll
    for (int nt = 0; nt < 4; nt++) {
        float bv = bias[nt * 16 + ln];
        acc[nt] = (f32x4){bv, bv, bv, bv};
    }
    #pragma unroll
    for (int kh = 0; kh < KH; kh++)
        #pragma unroll
        for (int nt = 0; nt < 4; nt++)
            acc[nt] = __builtin_amdgcn_mfma_f32_16x16x32_bf16(
                afrag[kh], bfrag[nt][kh], acc[nt], 0, 0, 0);

    #pragma unroll
    for (int reg = 0; reg < 4; reg++) {
        int row = nb + rw + q * 4 + reg;
        if (row < N)
            #pragma unroll
            for (int nt = 0; nt < 4; nt++)
                out[(size_t)row * 64 + nt * 16 + ln] = bf16_1(acc[nt][reg]);
    }

    // stats
    {
        float s1[4] = {0.f, 0.f, 0.f, 0.f};
        float s2[4] = {0.f, 0.f, 0.f, 0.f};
        #pragma unroll
        for (int reg = 0; reg < 4; reg++) {
            int row = nb + rw + q * 4 + reg;
            if (row < N)
                #pragma unroll
                for (int nt = 0; nt < 4; nt++) {
                    float v = acc[nt][reg];
                    s1[nt] += v;
                    s2[nt] += v * v;
                }
        }
        #pragma unroll
        for (int nt = 0; nt < 4; nt++) {
            s1[nt] += __shfl_xor(s1[nt], 16);
            s1[nt] += __shfl_xor(s1[nt], 32);
            s2[nt] += __shfl_xor(s2[nt], 16);
            s2[nt] += __shfl_xor(s2[nt], 32);
        }
        __syncthreads();
        if (l < 16) {
            #pragma unroll
            for (int nt = 0; nt < 4; nt++) {
                red[w * 64 + nt * 16 + l]        = s1[nt];
                red[256 + w * 64 + nt * 16 + l]  = s2[nt];
            }
        }
        __syncthreads();
        if (tid < 64) {
            float t1 = red[tid] + red[64 + tid] + red[128 + tid] + red[192 + tid];
            float t2 = red[256 + tid] + red[320 + tid] + red[384 + tid] + red[448 + tid];
            unsafeAtomicAdd(&stat_sum[tid],   t1);
            unsafeAtomicAdd(&stat_sumsq[tid], t2);
        }
    }
}

// ---------------------------------------------------------------------------
// Plain MFMA GEMM (encoder INK=1 fp32 input; GEMM2 INK=2 BN+ReLU from stats)
// Block: 256 thr / 4 waves; tile 64 rows x 64 cols.
template<int K, int INK, bool STATS>
__global__ __launch_bounds__(256)
void mfma_gemm(const void* __restrict__ Av,
               const float* __restrict__ bn_sum, const float* __restrict__ bn_sumsq,
               const float* __restrict__ gamma, const float* __restrict__ beta,
               float invN,
               const float* __restrict__ W, const float* __restrict__ bias,
               unsigned short* __restrict__ out,
               float* __restrict__ stat_sum, float* __restrict__ stat_sumsq,
               int N)
{
    constexpr int AS  = K + 8;
    constexpr int WS  = K + 8;
    constexpr int CPR = K / 8;
    constexpr int KH  = K / 32;

    __shared__ short a_lds[64 * AS];
    __shared__ short wt_lds[64 * WS];
    __shared__ float ssf[128];
    __shared__ float red[512];

    const int tid = threadIdx.x;
    const int nb  = blockIdx.x * 64;
    const int l   = tid & 63;
    const int w   = tid >> 6;      // 0..3
    const int ln  = l & 15;
    const int q   = l >> 4;

    if (INK == 2) {
        if (tid < 64) {
            float mu  = bn_sum[tid] * invN;
            float var = bn_sumsq[tid] * invN - mu * mu;
            float s   = gamma[tid] * rsqrtf(var + BN_EPS);
            ssf[tid]      = s;
            ssf[64 + tid] = beta[tid] - s * mu;
        }
        __syncthreads();
    }

    for (int idx = tid; idx < K * 64; idx += 256) {
        int k = idx >> 6, n = idx & 63;
        wt_lds[n * WS + k] = (short)bf16_1(W[idx]);
    }

    for (int c = tid; c < 64 * CPR; c += 256) {
        int rloc = c / CPR;
        int j    = c % CPR;
        int row  = nb + rloc;
        uint4 p = make_uint4(0u, 0u, 0u, 0u);
        if (row < N) {
            if (INK == 1) {
                const float4* xr = (const float4*)Av;
                float4 f0 = xr[(size_t)row * (K / 4) + 2 * j];
                float4 f1 = xr[(size_t)row * (K / 4) + 2 * j + 1];
                p.x = pack_bf16x2(f0.x, f0.y); p.y = pack_bf16x2(f0.z, f0.w);
                p.z = pack_bf16x2(f1.x, f1.y); p.w = pack_bf16x2(f1.z, f1.w);
            } else {
                p = ((const uint4*)Av)[(size_t)row * CPR + j];
                if (INK == 2) {
                    int k0 = j * 8;
                    unsigned int* pp = (unsigned int*)&p;
                    #pragma unroll
                    for (int t = 0; t < 4; t++) {
                        float2 f = unpack_bf16x2(pp[t]);
                        int k = k0 + 2 * t;
                        f.x = fmaxf(fmaf(f.x, ssf[k],     ssf[64 + k]),     0.f);
                        f.y = fmaxf(fmaf(f.y, ssf[k + 1], ssf[64 + k + 1]), 0.f);
                        pp[t] = pack_bf16x2(f.x, f.y);
                    }
                }
            }
        }
        *(uint4*)&a_lds[rloc * AS + j * 8] = p;
    }
    __syncthreads();

    short8 afrag[KH], bfrag[4][KH];
    const int rw = w * 16;
    #pragma unroll
    for (int kh = 0; kh < KH; kh++)
        afrag[kh] = *(const short8*)&a_lds[(rw + ln) * AS + kh * 32 + q * 8];
    #pragma unroll
    for (int nt = 0; nt < 4; nt++)
        #pragma unroll
        for (int kh = 0; kh < KH; kh++)
            bfrag[nt][kh] = *(const short8*)&wt_lds[(nt * 16 + ln) * WS + kh * 32 + q * 8];

    f32x4 acc[4];
    #pragma unroll
    for (int nt = 0; nt < 4; nt++) {
        float bv = bias[nt * 16 + ln];
        acc[nt] = (f32x4){bv, bv, bv, bv};
    }
    #pragma unroll
    for (int kh = 0; kh < KH; kh++)
        #pragma unroll
        for (int nt = 0; nt < 4; nt++)
            acc[nt] = __builtin_amdgcn_mfma_f32_16x16x32_bf16(
                afrag[kh], bfrag[nt][kh], acc[nt], 0, 0, 0);

    #pragma unroll
    for (int reg = 0; reg < 4; reg++) {
        int row = nb + rw + q * 4 + reg;
        if (row < N)
            #pragma unroll
            for (int nt = 0; nt < 4; nt++)
                out[(size_t)row * 64 + nt * 16 + ln] = bf16_1(acc[nt][reg]);
    }

    if (STATS) {
        float s1[4] = {0.f, 0.f, 0.f, 0.f};
        float s2[4] = {0.f, 0.f, 0.f, 0.f};
        #pragma unroll
        for (int reg = 0; reg < 4; reg++) {
            int row = nb + rw + q * 4 + reg;
            if (row < N)
                #pragma unroll
                for (int nt = 0; nt < 4; nt++) {
                    float v = acc[nt][reg];
                    s1[nt] += v;
                    s2[nt] += v * v;
                }
        }
        #pragma unroll
        for (int nt = 0; nt < 4; nt++) {
            s1[nt] += __shfl_xor(s1[nt], 16);
            s1[nt] += __shfl_xor(s1[nt], 32);
            s2[nt] += __shfl_xor(s2[nt], 16);
            s2[nt] += __shfl_xor(s2[nt], 32);
        }
        __syncthreads();
        if (l < 16) {
            #pragma unroll
            for (int nt = 0; nt < 4; nt++) {
                red[w * 64 + nt * 16 + l]       = s1[nt];
                red[256 + w * 64 + nt * 16 + l] = s2[nt];
            }
        }
        __syncthreads();
        if (tid < 64) {
            float t1 = red[tid] + red[64 + tid] + red[128 + tid] + red[192 + tid];
            float t2 = red[256 + tid] + red[320 + tid] + red[384 + tid] + red[448 + tid];
            unsafeAtomicAdd(&stat_sum[tid],   t1);
            unsafeAtomicAdd(&stat_sumsq[tid], t2);
        }
    }
}

// ---------------------------------------------------------------------------
// Bucketed CSR build (bucket = dst>>7, <=800 buckets)
__global__ __launch_bounds__(256)
void bucket_hist(const int* __restrict__ dst, int* __restrict__ bhist,
                 int E, int nb)
{
    __shared__ int lh[1024];
    for (int i = threadIdx.x; i < 1024; i += 256) lh[i] = 0;
    __syncthreads();
    for (int e = blockIdx.x * 256 + threadIdx.x; e < E; e += gridDim.x * 256)
        atomicAdd(&lh[dst[e] >> 7], 1);
    __syncthreads();
    for (int i = threadIdx.x; i < nb; i += 256)
        if (lh[i]) atomicAdd(&bhist[i], lh[i]);
}

__global__ __launch_bounds__(1024)
void bucket_scan(const int* __restrict__ bhist, int* __restrict__ bbase,
                 int* __restrict__ bcur, int nb)
{
    __shared__ int sm[1024];
    int t = threadIdx.x;
    int v = (t < nb) ? bhist[t] : 0;
    sm[t] = v; __syncthreads();
    for (int off = 1; off < 1024; off <<= 1) {
        int add = (t >= off) ? sm[t - off] : 0;
        __syncthreads();
        sm[t] += add;
        __syncthreads();
    }
    if (t <= nb) {
        int ex = sm[t] - v;
        bbase[t] = ex;
        if (t < nb) bcur[t * CURS_STRIDE] = ex;
    }
}

__global__ __launch_bounds__(256)
void bucket_scatter(const int* __restrict__ src, const int* __restrict__ dst,
                    int* __restrict__ bcur, int* __restrict__ ebuf,
                    int E, int nb)
{
    constexpr int CH = 4096;
    __shared__ int            key[CH];
    __shared__ unsigned short bid[CH];
    __shared__ int lh[800];
    __shared__ int lbase[800];

    const int t    = threadIdx.x;
    const int base = blockIdx.x * CH;
    const int cnt  = min(CH, E - base);

    for (int i = t; i < nb; i += 256) lh[i] = 0;
    __syncthreads();

    for (int i = t; i < cnt; i += 256) {
        int d = dst[base + i];
        int s = src[base + i];
        int b = d >> 7;
        key[i] = (s << 7) | (d & 127);
        bid[i] = (unsigned short)b;
        atomicAdd(&lh[b], 1);
    }
    __syncthreads();

    for (int i = t; i < nb; i += 256) {
        int c = lh[i];
        if (c) lbase[i] = atomicAdd(&bcur[i * CURS_STRIDE], c);
        lh[i] = 0;
    }
    __syncthreads();

    for (int i = t; i < cnt; i += 256) {
        int b = bid[i];
        int p = atomicAdd(&lh[b], 1);
        ebuf[lbase[b] + p] = key[i];
    }
}

__global__ __launch_bounds__(256)
void bucket_csr(const int* __restrict__ bbase, const int* __restrict__ ebuf,
                int* __restrict__ row, int* __restrict__ srcs, int N, int E)
{
    __shared__ int lh[128], lofs[128], lcur[128];
    const int b   = blockIdx.x;
    const int tid = threadIdx.x;
    const int beg = bbase[b], end = bbase[b + 1];

    if (tid < 128) lh[tid] = 0;
    __syncthreads();
    for (int e = beg + tid; e < end; e += 256)
        atomicAdd(&lh[ebuf[e] & 127], 1);
    __syncthreads();

    int v = (tid < 128) ? lh[tid] : 0;
    if (tid < 128) lofs[tid] = v;
    __syncthreads();
    for (int off = 1; off < 128; off <<= 1) {
        int add = 0;
        if (tid < 128 && tid >= off) add = lofs[tid - off];
        __syncthreads();
        if (tid < 128) lofs[tid] += add;
        __syncthreads();
    }
    if (tid < 128) {
        int ex = lofs[tid] - v;
        lcur[tid] = ex;
        int node = b * 128 + tid;
        if (node < N) row[node] = beg + ex;
    }
    if (b == 0 && tid == 0) row[N] = E;
    __syncthreads();

    for (int e = beg + tid; e < end; e += 256) {
        int pk = ebuf[e];
        int p = atomicAdd(&lcur[pk & 127], 1);
        srcs[beg + p] = pk >> 7;
    }
}

// ---------------------------------------------------------------------------
__global__ __launch_bounds__(256)
void pool_nodes(const unsigned short* __restrict__ hb,
                const float* __restrict__ bsum, const float* __restrict__ bsumsq,
                const float* __restrict__ gamma, const float* __restrict__ beta,
                float invN, const int* __restrict__ batch,
                float* __restrict__ pooled, int N)
{
    int d  = threadIdx.x & 63;
    int nl = threadIdx.x >> 6;
    int nb = blockIdx.x * 32;
    float mu  = bsum[d] * invN;
    float var = bsumsq[d] * invN - mu * mu;
    float s   = gamma[d] * rsqrtf(var + BN_EPS);
    float sh  = beta[d] - s * mu;
    float acc = 0.f;
    int cg = -1;
    #pragma unroll
    for (int r = 0; r < 8; r++) {
        int n = nb + nl * 8 + r;
        if (n >= N) break;
        int g = batch[n];
        if (g != cg) {
            if (cg >= 0) unsafeAtomicAdd(&pooled[(size_t)cg * 64 + d], acc);
            acc = 0.f; cg = g;
        }
        float v = __uint_as_float(((unsigned int)hb[(size_t)n * 64 + d]) << 16);
        acc += fmaxf(fmaf(v, s, sh), 0.f);
    }
    if (cg >= 0) unsafeAtomicAdd(&pooled[(size_t)cg * 64 + d], acc);
}

__global__ __launch_bounds__(256)
void pool_x(const float* __restrict__ x, const int* __restrict__ batch,
            float* __restrict__ px, int N)
{
    int f  = threadIdx.x & 31;
    int nl = threadIdx.x >> 5;
    int nb = blockIdx.x * 64;
    float acc = 0.f;
    int cg = -1;
    #pragma unroll
    for (int r = 0; r < 8; r++) {
        int n = nb + nl * 8 + r;
        if (n >= N) break;
        int g = batch[n];
        if (g != cg) {
            if (cg >= 0) unsafeAtomicAdd(&px[(size_t)cg * 32 + f], acc);
            acc = 0.f; cg = g;
        }
        acc += x[(size_t)n * 32 + f];
    }
    if (cg >= 0) unsafeAtomicAdd(&px[(size_t)cg * 32 + f], acc);
}

// ---------------------------------------------------------------------------
__global__ __launch_bounds__(256)
void head_kernel(const float* __restrict__ px, const float* __restrict__ pl,
                 const float* __restrict__ fcW0, const float* __restrict__ fcb0,
                 const float* __restrict__ fcW, const float* __restrict__ fcb,
                 const int* __restrict__ y, float* __restrict__ out, int G)
{
    int tid = blockIdx.x * 256 + threadIdx.x;
    int total = G * 10;
    if (tid < total) {
        int g = tid / 10, c = tid % 10;
        float acc = fcb0[c];
        const float* pxg = px + (size_t)g * 32;
        #pragma unroll
        for (int k = 0; k < 32; k++) acc = fmaf(pxg[k], fcW0[k * 10 + c], acc);
        #pragma unroll
        for (int i = 0; i < 4; i++) {
            acc += fcb[i * 10 + c];
            const float* pg = pl + ((size_t)i * G + g) * 64;
            const float* w  = fcW + i * 640;
            #pragma unroll
            for (int k = 0; k < 64; k++) acc = fmaf(pg[k], w[k * 10 + c], acc);
        }
        out[tid] = acc;
    } else if (tid < total + G) {
        out[tid] = (float)y[tid - total];
    }
}

// ---------------------------------------------------------------------------
extern "C" void kernel_launch(void* const* d_in, const int* in_sizes, int n_in,
                              void* d_out, int out_size, void* d_ws, size_t ws_size,
                              hipStream_t stream)
{
    const float* x     = (const float*)d_in[0];
    const int*   ei    = (const int*)  d_in[1];
    const int*   batch = (const int*)  d_in[2];
    const int*   y     = (const int*)  d_in[3];
    const float* W_enc = (const float*)d_in[4];
    const float* b_enc = (const float*)d_in[5];
    const float* W1    = (const float*)d_in[6];
    const float* b1    = (const float*)d_in[7];
    const float* g1    = (const float*)d_in[8];
    const float* be1   = (const float*)d_in[9];
    const float* W2    = (const float*)d_in[10];
    const float* b2    = (const float*)d_in[11];
    const float* gout  = (const float*)d_in[12];
    const float* bout  = (const float*)d_in[13];
    const float* fcW0  = (const float*)d_in[14];
    const float* fcb0  = (const float*)d_in[15];
    const float* fcW   = (const float*)d_in[16];
    const float* fcb   = (const float*)d_in[17];

    const int N = in_sizes[0] / 32;   // 100000
    const int E = in_sizes[1] / 2;    // 1600000
    const int G = in_sizes[3];        // 2000
    const int* src = ei;
    const int* dst = ei + E;
    const int NB = (N + 127) / 128;   // 782 buckets

    // ws layout: m bf16 | hb bf16 | stats | px | pl | row | srcs
    unsigned int* m  = (unsigned int*)d_ws;          // N*32 uints
    unsigned int* hb = m + (size_t)N * 32;           // N*32 uints
    float* stats = (float*)(hb + (size_t)N * 32);    // [4][2] x 128
    float* px    = stats + 1024;                     // G*32
    float* pl    = px + (size_t)G * 32;              // 4*G*64
    int*   row   = (int*)(pl + (size_t)4 * G * 64);  // N+1
    int*   srcs  = row + (N + 1);                    // E
    // CSR temps alias m (dead before GEMM1 writes m)
    int*   mi    = (int*)m;
    int*   bhist = mi;
    int*   bbase = mi + 1024;
    int*   bcur  = mi + 2048;
    int*   ebuf  = mi + 2048 + 800 * CURS_STRIDE;

    size_t zbytes = (size_t)(1024 + G * 32 + 4 * G * 64) * sizeof(float);
    hipMemsetAsync(stats, 0, zbytes, stream);
    hipMemsetAsync(bhist, 0, 1024 * sizeof(int), stream);

    // bucketed CSR build
    bucket_hist<<<160, 256, 0, stream>>>(dst, bhist, E, NB);
    bucket_scan<<<1, 1024, 0, stream>>>(bhist, bbase, bcur, NB);
    bucket_scatter<<<(E + 4095) / 4096, 256, 0, stream>>>(src, dst, bcur, ebuf, E, NB);
    bucket_csr<<<NB, 256, 0, stream>>>(bbase, ebuf, row, srcs, N, E);

    const int gb = (N + 63) / 64;     // 1563 blocks (~6.1/CU)
    const float invN = 1.0f / (float)N;

    // encoder: hb = bf16(x @ W_enc + b_enc)
    mfma_gemm<32, 1, false><<<gb, 256, 0, stream>>>(
        x, nullptr, nullptr, nullptr, nullptr, 0.f,
        W_enc, b_enc, (unsigned short*)hb, nullptr, nullptr, N);
    pool_x<<<(N + 63) / 64, 256, 0, stream>>>(x, batch, px, N);

    for (int i = 0; i < 4; i++) {
        float* s1a = stats + (i * 2 + 0) * 128;
        float* s1b = s1a + 64;
        float* s2a = stats + (i * 2 + 1) * 128;
        float* s2b = s2a + 64;

        // m = bf16( (t(hb[n]) + sum t(hb[nbr])) @ W1 + b1 ) + stats s1 (fused)
        if (i == 0) {
            gin_gemm1<false><<<gb, 256, 0, stream>>>(
                row, srcs, hb, nullptr, nullptr, nullptr, nullptr, 0.f,
                W1 + (size_t)i * 4096, b1 + i * 64, (unsigned short*)m, s1a, s1b, N);
        } else {
            float* p2a = stats + ((i - 1) * 2 + 1) * 128;
            float* p2b = p2a + 64;
            gin_gemm1<true><<<gb, 256, 0, stream>>>(
                row, srcs, hb, p2a, p2b,
                gout + (i - 1) * 64, bout + (i - 1) * 64, invN,
                W1 + (size_t)i * 4096, b1 + i * 64, (unsigned short*)m, s1a, s1b, N);
        }

        // hb = bf16( relu(bn1(m)) @ W2[i] + b2[i] ) + stats s2
        mfma_gemm<64, 2, true><<<gb, 256, 0, stream>>>(
            m, s1a, s1b, g1 + i * 64, be1 + i * 64, invN,
            W2 + (size_t)i * 4096, b2 + i * 64, (unsigned short*)hb, s2a, s2b, N);

        // pl[i][g] += relu(bn2(hb))
        pool_nodes<<<(N + 31) / 32, 256, 0, stream>>>(
            (const unsigned short*)hb, s2a, s2b, gout + i * 64, bout + i * 64, invN,
            batch, pl + (size_t)i * G * 64, N);
    }

    head_kernel<<<(G * 10 + G + 255) / 256, 256, 0, stream>>>(
        px, pl, fcW0, fcb0, fcW, fcb, y, (float*)d_out, G);
}

// Round 7
// 520.878 us; speedup vs baseline: 1.3088x; 1.3088x over previous
//
#include <hip/hip_runtime.h>

// GIN round 15: revert to R12 shape (verified best: 128-row tile, 512 thr,
// 8-deep gather, 545us). Single change: the gather remainder (4-wide chunk +
// serial singles, a dependent-latency chain on every row) is replaced by ONE
// predicated 8-wide chunk: indices clamped to min(e+j,end-1) (always-valid
// load, issues in parallel), accumulation masked via fmaf(val, mask, acc).
// R14's 64-row tiles regressed (2x per-block fixed costs) -> reverted.
// MFMA bf16 GEMMs, bf16 h/m, bucketed CSR, folded BN, run-length pooling.

#define BN_EPS 1e-5f
#define CURS_STRIDE 16

typedef __attribute__((ext_vector_type(8))) short short8;
typedef __attribute__((ext_vector_type(4))) float f32x4;

// ---- bf16 helpers (rne) ----
__device__ __forceinline__ unsigned int pack_bf16x2(float a, float b) {
    unsigned int ua = __float_as_uint(a);
    unsigned int ub = __float_as_uint(b);
    ua = (ua + 0x7FFFu + ((ua >> 16) & 1u)) >> 16;
    ub = (ub + 0x7FFFu + ((ub >> 16) & 1u)) >> 16;
    return ua | (ub << 16);
}
__device__ __forceinline__ unsigned short bf16_1(float f) {
    unsigned int u = __float_as_uint(f);
    u = (u + 0x7FFFu + ((u >> 16) & 1u)) >> 16;
    return (unsigned short)u;
}
__device__ __forceinline__ float2 unpack_bf16x2(unsigned int u) {
    float2 r;
    r.x = __uint_as_float(u << 16);
    r.y = __uint_as_float(u & 0xFFFF0000u);
    return r;
}

template<bool BN>
__device__ __forceinline__ void acc_row8(float (&acc)[8], uint4 p,
                                         const float* sc, const float* sh) {
    unsigned int pp[4] = {p.x, p.y, p.z, p.w};
    #pragma unroll
    for (int t = 0; t < 4; t++) {
        float2 f = unpack_bf16x2(pp[t]);
        if (BN) {
            f.x = fmaxf(fmaf(f.x, sc[2 * t],     sh[2 * t]),     0.f);
            f.y = fmaxf(fmaf(f.y, sc[2 * t + 1], sh[2 * t + 1]), 0.f);
        }
        acc[2 * t]     += f.x;
        acc[2 * t + 1] += f.y;
    }
}

// masked variant: acc += t(p) * m   (m = 0 or 1)
template<bool BN>
__device__ __forceinline__ void acc_row8m(float (&acc)[8], uint4 p,
                                          const float* sc, const float* sh,
                                          float m) {
    unsigned int pp[4] = {p.x, p.y, p.z, p.w};
    #pragma unroll
    for (int t = 0; t < 4; t++) {
        float2 f = unpack_bf16x2(pp[t]);
        if (BN) {
            f.x = fmaxf(fmaf(f.x, sc[2 * t],     sh[2 * t]),     0.f);
            f.y = fmaxf(fmaf(f.y, sc[2 * t + 1], sh[2 * t + 1]), 0.f);
        }
        acc[2 * t]     = fmaf(f.x, m, acc[2 * t]);
        acc[2 * t + 1] = fmaf(f.y, m, acc[2 * t + 1]);
    }
}

// ---------------------------------------------------------------------------
// Fused GIN conv stage 1: A[n] = t(hb[n]) + sum_{s in nbrs(n)} t(hb[s]),
// out = bf16(A @ W1 + b1), column stats of out -> s1. t = BN?relu(v*s+sh):v.
// Block: 512 thr / 8 waves; tile 128 rows x 64 cols; 8-deep gather,
// predicated 8-wide tail (no serial remainder chain).
template<bool BN>
__global__ __launch_bounds__(512)
void gin_gemm1(const int* __restrict__ rowp, const int* __restrict__ srcs,
               const unsigned int* __restrict__ hb,
               const float* __restrict__ bsum, const float* __restrict__ bsumsq,
               const float* __restrict__ gamma, const float* __restrict__ beta,
               float invN,
               const float* __restrict__ W, const float* __restrict__ bias,
               unsigned short* __restrict__ out,
               float* __restrict__ stat_sum, float* __restrict__ stat_sumsq,
               int N)
{
    constexpr int AS = 72, WS = 72, KH = 2;
    __shared__ short a_lds[128 * AS];
    __shared__ short wt_lds[64 * WS];
    __shared__ float ssf[128];
    __shared__ float red[1024];

    const int tid = threadIdx.x;
    const int nb  = blockIdx.x * 128;
    const int l   = tid & 63;
    const int w   = tid >> 6;      // 0..7
    const int ln  = l & 15;
    const int q   = l >> 4;

    if (BN) {
        if (tid < 64) {
            float mu  = bsum[tid] * invN;
            float var = bsumsq[tid] * invN - mu * mu;
            float s   = gamma[tid] * rsqrtf(var + BN_EPS);
            ssf[tid]      = s;
            ssf[64 + tid] = beta[tid] - s * mu;
        }
        __syncthreads();
    }

    // stage W^T bf16
    for (int idx = tid; idx < 64 * 64; idx += 512) {
        int k = idx >> 6, n = idx & 63;
        wt_lds[n * WS + k] = (short)bf16_1(W[idx]);
    }

    // gather: 8 lanes/row, uint4 (8 bf16)/lane; thread owns rows rl, 64+rl
    const uint4* hb4 = (const uint4*)hb;
    const int cc = tid & 7;
    const int rl = tid >> 3;       // 0..63
    float sc[8], sh[8];
    if (BN) {
        #pragma unroll
        for (int j = 0; j < 8; j++) {
            sc[j] = ssf[cc * 8 + j];
            sh[j] = ssf[64 + cc * 8 + j];
        }
    }
    #pragma unroll
    for (int it = 0; it < 2; it++) {
        int rloc = it * 64 + rl;
        int n = nb + rloc;
        float acc[8] = {0.f, 0.f, 0.f, 0.f, 0.f, 0.f, 0.f, 0.f};
        if (n < N) {
            uint4 p = hb4[(size_t)n * 8 + cc];
            acc_row8<BN>(acc, p, sc, sh);
            int e = rowp[n], end = rowp[n + 1];
            // full 8-wide chunks: 8 independent gathers in flight
            for (; e + 7 < end; e += 8) {
                int a0 = srcs[e],     a1 = srcs[e + 1];
                int a2 = srcs[e + 2], a3 = srcs[e + 3];
                int a4 = srcs[e + 4], a5 = srcs[e + 5];
                int a6 = srcs[e + 6], a7 = srcs[e + 7];
                uint4 p0 = hb4[(size_t)a0 * 8 + cc];
                uint4 p1 = hb4[(size_t)a1 * 8 + cc];
                uint4 p2 = hb4[(size_t)a2 * 8 + cc];
                uint4 p3 = hb4[(size_t)a3 * 8 + cc];
                uint4 p4 = hb4[(size_t)a4 * 8 + cc];
                uint4 p5 = hb4[(size_t)a5 * 8 + cc];
                uint4 p6 = hb4[(size_t)a6 * 8 + cc];
                uint4 p7 = hb4[(size_t)a7 * 8 + cc];
                acc_row8<BN>(acc, p0, sc, sh);
                acc_row8<BN>(acc, p1, sc, sh);
                acc_row8<BN>(acc, p2, sc, sh);
                acc_row8<BN>(acc, p3, sc, sh);
                acc_row8<BN>(acc, p4, sc, sh);
                acc_row8<BN>(acc, p5, sc, sh);
                acc_row8<BN>(acc, p6, sc, sh);
                acc_row8<BN>(acc, p7, sc, sh);
            }
            // predicated 8-wide tail: all loads issue in parallel, masked acc
            if (e < end) {
                int last = end - 1;
                int i0 = min(e + 0, last), i1 = min(e + 1, last);
                int i2 = min(e + 2, last), i3 = min(e + 3, last);
                int i4 = min(e + 4, last), i5 = min(e + 5, last);
                int i6 = min(e + 6, last), i7 = min(e + 7, last);
                int b0 = srcs[i0], b1 = srcs[i1], b2 = srcs[i2], b3 = srcs[i3];
                int b4 = srcs[i4], b5 = srcs[i5], b6 = srcs[i6], b7 = srcs[i7];
                uint4 p0 = hb4[(size_t)b0 * 8 + cc];
                uint4 p1 = hb4[(size_t)b1 * 8 + cc];
                uint4 p2 = hb4[(size_t)b2 * 8 + cc];
                uint4 p3 = hb4[(size_t)b3 * 8 + cc];
                uint4 p4 = hb4[(size_t)b4 * 8 + cc];
                uint4 p5 = hb4[(size_t)b5 * 8 + cc];
                uint4 p6 = hb4[(size_t)b6 * 8 + cc];
                uint4 p7 = hb4[(size_t)b7 * 8 + cc];
                acc_row8m<BN>(acc, p0, sc, sh, 1.f);  // e+0 < end guaranteed
                acc_row8m<BN>(acc, p1, sc, sh, (e + 1 < end) ? 1.f : 0.f);
                acc_row8m<BN>(acc, p2, sc, sh, (e + 2 < end) ? 1.f : 0.f);
                acc_row8m<BN>(acc, p3, sc, sh, (e + 3 < end) ? 1.f : 0.f);
                acc_row8m<BN>(acc, p4, sc, sh, (e + 4 < end) ? 1.f : 0.f);
                acc_row8m<BN>(acc, p5, sc, sh, (e + 5 < end) ? 1.f : 0.f);
                acc_row8m<BN>(acc, p6, sc, sh, (e + 6 < end) ? 1.f : 0.f);
                acc_row8m<BN>(acc, p7, sc, sh, (e + 7 < end) ? 1.f : 0.f);
            }
        }
        uint4 o;
        o.x = pack_bf16x2(acc[0], acc[1]);
        o.y = pack_bf16x2(acc[2], acc[3]);
        o.z = pack_bf16x2(acc[4], acc[5]);
        o.w = pack_bf16x2(acc[6], acc[7]);
        *(uint4*)&a_lds[rloc * AS + cc * 8] = o;
    }
    __syncthreads();

    // fragments: one 16x64 row-tile per wave
    short8 afrag[KH], bfrag[4][KH];
    const int rw = w * 16;
    #pragma unroll
    for (int kh = 0; kh < KH; kh++)
        afrag[kh] = *(const short8*)&a_lds[(rw + ln) * AS + kh * 32 + q * 8];
    #pragma unroll
    for (int nt = 0; nt < 4; nt++)
        #pragma unroll
        for (int kh = 0; kh < KH; kh++)
            bfrag[nt][kh] = *(const short8*)&wt_lds[(nt * 16 + ln) * WS + kh * 32 + q * 8];

    f32x4 acc[4];
    #pragma unroll
    for (int nt = 0; nt < 4; nt++) {
        float bv = bias[nt * 16 + ln];
        acc[nt] = (f32x4){bv, bv, bv, bv};
    }
    #pragma unroll
    for (int kh = 0; kh < KH; kh++)
        #pragma unroll
        for (int nt = 0; nt < 4; nt++)
            acc[nt] = __builtin_amdgcn_mfma_f32_16x16x32_bf16(
                afrag[kh], bfrag[nt][kh], acc[nt], 0, 0, 0);

    #pragma unroll
    for (int reg = 0; reg < 4; reg++) {
        int row = nb + rw + q * 4 + reg;
        if (row < N)
            #pragma unroll
            for (int nt = 0; nt < 4; nt++)
                out[(size_t)row * 64 + nt * 16 + ln] = bf16_1(acc[nt][reg]);
    }

    // stats
    {
        float s1[4] = {0.f, 0.f, 0.f, 0.f};
        float s2[4] = {0.f, 0.f, 0.f, 0.f};
        #pragma unroll
        for (int reg = 0; reg < 4; reg++) {
            int row = nb + rw + q * 4 + reg;
            if (row < N)
                #pragma unroll
                for (int nt = 0; nt < 4; nt++) {
                    float v = acc[nt][reg];
                    s1[nt] += v;
                    s2[nt] += v * v;
                }
        }
        #pragma unroll
        for (int nt = 0; nt < 4; nt++) {
            s1[nt] += __shfl_xor(s1[nt], 16);
            s1[nt] += __shfl_xor(s1[nt], 32);
            s2[nt] += __shfl_xor(s2[nt], 16);
            s2[nt] += __shfl_xor(s2[nt], 32);
        }
        __syncthreads();
        if (l < 16) {
            #pragma unroll
            for (int nt = 0; nt < 4; nt++) {
                red[w * 64 + nt * 16 + l]        = s1[nt];
                red[512 + w * 64 + nt * 16 + l]  = s2[nt];
            }
        }
        __syncthreads();
        if (tid < 64) {
            float t1 = 0.f, t2 = 0.f;
            #pragma unroll
            for (int j = 0; j < 8; j++) {
                t1 += red[j * 64 + tid];
                t2 += red[512 + j * 64 + tid];
            }
            unsafeAtomicAdd(&stat_sum[tid],   t1);
            unsafeAtomicAdd(&stat_sumsq[tid], t2);
        }
    }
}

// ---------------------------------------------------------------------------
// Plain MFMA GEMM (encoder INK=1 fp32 input; GEMM2 INK=2 BN+ReLU from stats)
// Block: 512 thr / 8 waves; tile 128 rows x 64 cols.
template<int K, int INK, bool STATS>
__global__ __launch_bounds__(512)
void mfma_gemm(const void* __restrict__ Av,
               const float* __restrict__ bn_sum, const float* __restrict__ bn_sumsq,
               const float* __restrict__ gamma, const float* __restrict__ beta,
               float invN,
               const float* __restrict__ W, const float* __restrict__ bias,
               unsigned short* __restrict__ out,
               float* __restrict__ stat_sum, float* __restrict__ stat_sumsq,
               int N)
{
    constexpr int AS  = K + 8;
    constexpr int WS  = K + 8;
    constexpr int CPR = K / 8;
    constexpr int KH  = K / 32;

    __shared__ short a_lds[128 * AS];
    __shared__ short wt_lds[64 * WS];
    __shared__ float ssf[128];
    __shared__ float red[1024];

    const int tid = threadIdx.x;
    const int nb  = blockIdx.x * 128;
    const int l   = tid & 63;
    const int w   = tid >> 6;      // 0..7
    const int ln  = l & 15;
    const int q   = l >> 4;

    if (INK == 2) {
        if (tid < 64) {
            float mu  = bn_sum[tid] * invN;
            float var = bn_sumsq[tid] * invN - mu * mu;
            float s   = gamma[tid] * rsqrtf(var + BN_EPS);
            ssf[tid]      = s;
            ssf[64 + tid] = beta[tid] - s * mu;
        }
        __syncthreads();
    }

    for (int idx = tid; idx < K * 64; idx += 512) {
        int k = idx >> 6, n = idx & 63;
        wt_lds[n * WS + k] = (short)bf16_1(W[idx]);
    }

    for (int c = tid; c < 128 * CPR; c += 512) {
        int rloc = c / CPR;
        int j    = c % CPR;
        int row  = nb + rloc;
        uint4 p = make_uint4(0u, 0u, 0u, 0u);
        if (row < N) {
            if (INK == 1) {
                const float4* xr = (const float4*)Av;
                float4 f0 = xr[(size_t)row * (K / 4) + 2 * j];
                float4 f1 = xr[(size_t)row * (K / 4) + 2 * j + 1];
                p.x = pack_bf16x2(f0.x, f0.y); p.y = pack_bf16x2(f0.z, f0.w);
                p.z = pack_bf16x2(f1.x, f1.y); p.w = pack_bf16x2(f1.z, f1.w);
            } else {
                p = ((const uint4*)Av)[(size_t)row * CPR + j];
                if (INK == 2) {
                    int k0 = j * 8;
                    unsigned int* pp = (unsigned int*)&p;
                    #pragma unroll
                    for (int t = 0; t < 4; t++) {
                        float2 f = unpack_bf16x2(pp[t]);
                        int k = k0 + 2 * t;
                        f.x = fmaxf(fmaf(f.x, ssf[k],     ssf[64 + k]),     0.f);
                        f.y = fmaxf(fmaf(f.y, ssf[k + 1], ssf[64 + k + 1]), 0.f);
                        pp[t] = pack_bf16x2(f.x, f.y);
                    }
                }
            }
        }
        *(uint4*)&a_lds[rloc * AS + j * 8] = p;
    }
    __syncthreads();

    short8 afrag[KH], bfrag[4][KH];
    const int rw = w * 16;
    #pragma unroll
    for (int kh = 0; kh < KH; kh++)
        afrag[kh] = *(const short8*)&a_lds[(rw + ln) * AS + kh * 32 + q * 8];
    #pragma unroll
    for (int nt = 0; nt < 4; nt++)
        #pragma unroll
        for (int kh = 0; kh < KH; kh++)
            bfrag[nt][kh] = *(const short8*)&wt_lds[(nt * 16 + ln) * WS + kh * 32 + q * 8];

    f32x4 acc[4];
    #pragma unroll
    for (int nt = 0; nt < 4; nt++) {
        float bv = bias[nt * 16 + ln];
        acc[nt] = (f32x4){bv, bv, bv, bv};
    }
    #pragma unroll
    for (int kh = 0; kh < KH; kh++)
        #pragma unroll
        for (int nt = 0; nt < 4; nt++)
            acc[nt] = __builtin_amdgcn_mfma_f32_16x16x32_bf16(
                afrag[kh], bfrag[nt][kh], acc[nt], 0, 0, 0);

    #pragma unroll
    for (int reg = 0; reg < 4; reg++) {
        int row = nb + rw + q * 4 + reg;
        if (row < N)
            #pragma unroll
            for (int nt = 0; nt < 4; nt++)
                out[(size_t)row * 64 + nt * 16 + ln] = bf16_1(acc[nt][reg]);
    }

    if (STATS) {
        float s1[4] = {0.f, 0.f, 0.f, 0.f};
        float s2[4] = {0.f, 0.f, 0.f, 0.f};
        #pragma unroll
        for (int reg = 0; reg < 4; reg++) {
            int row = nb + rw + q * 4 + reg;
            if (row < N)
                #pragma unroll
                for (int nt = 0; nt < 4; nt++) {
                    float v = acc[nt][reg];
                    s1[nt] += v;
                    s2[nt] += v * v;
                }
        }
        #pragma unroll
        for (int nt = 0; nt < 4; nt++) {
            s1[nt] += __shfl_xor(s1[nt], 16);
            s1[nt] += __shfl_xor(s1[nt], 32);
            s2[nt] += __shfl_xor(s2[nt], 16);
            s2[nt] += __shfl_xor(s2[nt], 32);
        }
        __syncthreads();
        if (l < 16) {
            #pragma unroll
            for (int nt = 0; nt < 4; nt++) {
                red[w * 64 + nt * 16 + l]       = s1[nt];
                red[512 + w * 64 + nt * 16 + l] = s2[nt];
            }
        }
        __syncthreads();
        if (tid < 64) {
            float t1 = 0.f, t2 = 0.f;
            #pragma unroll
            for (int j = 0; j < 8; j++) {
                t1 += red[j * 64 + tid];
                t2 += red[512 + j * 64 + tid];
            }
            unsafeAtomicAdd(&stat_sum[tid],   t1);
            unsafeAtomicAdd(&stat_sumsq[tid], t2);
        }
    }
}

// ---------------------------------------------------------------------------
// Bucketed CSR build (bucket = dst>>7, <=800 buckets)
__global__ __launch_bounds__(256)
void bucket_hist(const int* __restrict__ dst, int* __restrict__ bhist,
                 int E, int nb)
{
    __shared__ int lh[1024];
    for (int i = threadIdx.x; i < 1024; i += 256) lh[i] = 0;
    __syncthreads();
    for (int e = blockIdx.x * 256 + threadIdx.x; e < E; e += gridDim.x * 256)
        atomicAdd(&lh[dst[e] >> 7], 1);
    __syncthreads();
    for (int i = threadIdx.x; i < nb; i += 256)
        if (lh[i]) atomicAdd(&bhist[i], lh[i]);
}

__global__ __launch_bounds__(1024)
void bucket_scan(const int* __restrict__ bhist, int* __restrict__ bbase,
                 int* __restrict__ bcur, int nb)
{
    __shared__ int sm[1024];
    int t = threadIdx.x;
    int v = (t < nb) ? bhist[t] : 0;
    sm[t] = v; __syncthreads();
    for (int off = 1; off < 1024; off <<= 1) {
        int add = (t >= off) ? sm[t - off] : 0;
        __syncthreads();
        sm[t] += add;
        __syncthreads();
    }
    if (t <= nb) {
        int ex = sm[t] - v;
        bbase[t] = ex;
        if (t < nb) bcur[t * CURS_STRIDE] = ex;
    }
}

__global__ __launch_bounds__(256)
void bucket_scatter(const int* __restrict__ src, const int* __restrict__ dst,
                    int* __restrict__ bcur, int* __restrict__ ebuf,
                    int E, int nb)
{
    constexpr int CH = 4096;
    __shared__ int            key[CH];
    __shared__ unsigned short bid[CH];
    __shared__ int lh[800];
    __shared__ int lbase[800];

    const int t    = threadIdx.x;
    const int base = blockIdx.x * CH;
    const int cnt  = min(CH, E - base);

    for (int i = t; i < nb; i += 256) lh[i] = 0;
    __syncthreads();

    for (int i = t; i < cnt; i += 256) {
        int d = dst[base + i];
        int s = src[base + i];
        int b = d >> 7;
        key[i] = (s << 7) | (d & 127);
        bid[i] = (unsigned short)b;
        atomicAdd(&lh[b], 1);
    }
    __syncthreads();

    for (int i = t; i < nb; i += 256) {
        int c = lh[i];
        if (c) lbase[i] = atomicAdd(&bcur[i * CURS_STRIDE], c);
        lh[i] = 0;
    }
    __syncthreads();

    for (int i = t; i < cnt; i += 256) {
        int b = bid[i];
        int p = atomicAdd(&lh[b], 1);
        ebuf[lbase[b] + p] = key[i];
    }
}

__global__ __launch_bounds__(256)
void bucket_csr(const int* __restrict__ bbase, const int* __restrict__ ebuf,
                int* __restrict__ row, int* __restrict__ srcs, int N, int E)
{
    __shared__ int lh[128], lofs[128], lcur[128];
    const int b   = blockIdx.x;
    const int tid = threadIdx.x;
    const int beg = bbase[b], end = bbase[b + 1];

    if (tid < 128) lh[tid] = 0;
    __syncthreads();
    for (int e = beg + tid; e < end; e += 256)
        atomicAdd(&lh[ebuf[e] & 127], 1);
    __syncthreads();

    int v = (tid < 128) ? lh[tid] : 0;
    if (tid < 128) lofs[tid] = v;
    __syncthreads();
    for (int off = 1; off < 128; off <<= 1) {
        int add = 0;
        if (tid < 128 && tid >= off) add = lofs[tid - off];
        __syncthreads();
        if (tid < 128) lofs[tid] += add;
        __syncthreads();
    }
    if (tid < 128) {
        int ex = lofs[tid] - v;
        lcur[tid] = ex;
        int node = b * 128 + tid;
        if (node < N) row[node] = beg + ex;
    }
    if (b == 0 && tid == 0) row[N] = E;
    __syncthreads();

    for (int e = beg + tid; e < end; e += 256) {
        int pk = ebuf[e];
        int p = atomicAdd(&lcur[pk & 127], 1);
        srcs[beg + p] = pk >> 7;
    }
}

// ---------------------------------------------------------------------------
__global__ __launch_bounds__(256)
void pool_nodes(const unsigned short* __restrict__ hb,
                const float* __restrict__ bsum, const float* __restrict__ bsumsq,
                const float* __restrict__ gamma, const float* __restrict__ beta,
                float invN, const int* __restrict__ batch,
                float* __restrict__ pooled, int N)
{
    int d  = threadIdx.x & 63;
    int nl = threadIdx.x >> 6;
    int nb = blockIdx.x * 32;
    float mu  = bsum[d] * invN;
    float var = bsumsq[d] * invN - mu * mu;
    float s   = gamma[d] * rsqrtf(var + BN_EPS);
    float sh  = beta[d] - s * mu;
    float acc = 0.f;
    int cg = -1;
    #pragma unroll
    for (int r = 0; r < 8; r++) {
        int n = nb + nl * 8 + r;
        if (n >= N) break;
        int g = batch[n];
        if (g != cg) {
            if (cg >= 0) unsafeAtomicAdd(&pooled[(size_t)cg * 64 + d], acc);
            acc = 0.f; cg = g;
        }
        float v = __uint_as_float(((unsigned int)hb[(size_t)n * 64 + d]) << 16);
        acc += fmaxf(fmaf(v, s, sh), 0.f);
    }
    if (cg >= 0) unsafeAtomicAdd(&pooled[(size_t)cg * 64 + d], acc);
}

__global__ __launch_bounds__(256)
void pool_x(const float* __restrict__ x, const int* __restrict__ batch,
            float* __restrict__ px, int N)
{
    int f  = threadIdx.x & 31;
    int nl = threadIdx.x >> 5;
    int nb = blockIdx.x * 64;
    float acc = 0.f;
    int cg = -1;
    #pragma unroll
    for (int r = 0; r < 8; r++) {
        int n = nb + nl * 8 + r;
        if (n >= N) break;
        int g = batch[n];
        if (g != cg) {
            if (cg >= 0) unsafeAtomicAdd(&px[(size_t)cg * 32 + f], acc);
            acc = 0.f; cg = g;
        }
        acc += x[(size_t)n * 32 + f];
    }
    if (cg >= 0) unsafeAtomicAdd(&px[(size_t)cg * 32 + f], acc);
}

// ---------------------------------------------------------------------------
__global__ __launch_bounds__(256)
void head_kernel(const float* __restrict__ px, const float* __restrict__ pl,
                 const float* __restrict__ fcW0, const float* __restrict__ fcb0,
                 const float* __restrict__ fcW, const float* __restrict__ fcb,
                 const int* __restrict__ y, float* __restrict__ out, int G)
{
    int tid = blockIdx.x * 256 + threadIdx.x;
    int total = G * 10;
    if (tid < total) {
        int g = tid / 10, c = tid % 10;
        float acc = fcb0[c];
        const float* pxg = px + (size_t)g * 32;
        #pragma unroll
        for (int k = 0; k < 32; k++) acc = fmaf(pxg[k], fcW0[k * 10 + c], acc);
        #pragma unroll
        for (int i = 0; i < 4; i++) {
            acc += fcb[i * 10 + c];
            const float* pg = pl + ((size_t)i * G + g) * 64;
            const float* w  = fcW + i * 640;
            #pragma unroll
            for (int k = 0; k < 64; k++) acc = fmaf(pg[k], w[k * 10 + c], acc);
        }
        out[tid] = acc;
    } else if (tid < total + G) {
        out[tid] = (float)y[tid - total];
    }
}

// ---------------------------------------------------------------------------
extern "C" void kernel_launch(void* const* d_in, const int* in_sizes, int n_in,
                              void* d_out, int out_size, void* d_ws, size_t ws_size,
                              hipStream_t stream)
{
    const float* x     = (const float*)d_in[0];
    const int*   ei    = (const int*)  d_in[1];
    const int*   batch = (const int*)  d_in[2];
    const int*   y     = (const int*)  d_in[3];
    const float* W_enc = (const float*)d_in[4];
    const float* b_enc = (const float*)d_in[5];
    const float* W1    = (const float*)d_in[6];
    const float* b1    = (const float*)d_in[7];
    const float* g1    = (const float*)d_in[8];
    const float* be1   = (const float*)d_in[9];
    const float* W2    = (const float*)d_in[10];
    const float* b2    = (const float*)d_in[11];
    const float* gout  = (const float*)d_in[12];
    const float* bout  = (const float*)d_in[13];
    const float* fcW0  = (const float*)d_in[14];
    const float* fcb0  = (const float*)d_in[15];
    const float* fcW   = (const float*)d_in[16];
    const float* fcb   = (const float*)d_in[17];

    const int N = in_sizes[0] / 32;   // 100000
    const int E = in_sizes[1] / 2;    // 1600000
    const int G = in_sizes[3];        // 2000
    const int* src = ei;
    const int* dst = ei + E;
    const int NB = (N + 127) / 128;   // 782 buckets

    // ws layout: m bf16 | hb bf16 | stats | px | pl | row | srcs
    unsigned int* m  = (unsigned int*)d_ws;          // N*32 uints
    unsigned int* hb = m + (size_t)N * 32;           // N*32 uints
    float* stats = (float*)(hb + (size_t)N * 32);    // [4][2] x 128
    float* px    = stats + 1024;                     // G*32
    float* pl    = px + (size_t)G * 32;              // 4*G*64
    int*   row   = (int*)(pl + (size_t)4 * G * 64);  // N+1
    int*   srcs  = row + (N + 1);                    // E
    // CSR temps alias m (dead before GEMM1 writes m)
    int*   mi    = (int*)m;
    int*   bhist = mi;
    int*   bbase = mi + 1024;
    int*   bcur  = mi + 2048;
    int*   ebuf  = mi + 2048 + 800 * CURS_STRIDE;

    size_t zbytes = (size_t)(1024 + G * 32 + 4 * G * 64) * sizeof(float);
    hipMemsetAsync(stats, 0, zbytes, stream);
    hipMemsetAsync(bhist, 0, 1024 * sizeof(int), stream);

    // bucketed CSR build
    bucket_hist<<<160, 256, 0, stream>>>(dst, bhist, E, NB);
    bucket_scan<<<1, 1024, 0, stream>>>(bhist, bbase, bcur, NB);
    bucket_scatter<<<(E + 4095) / 4096, 256, 0, stream>>>(src, dst, bcur, ebuf, E, NB);
    bucket_csr<<<NB, 256, 0, stream>>>(bbase, ebuf, row, srcs, N, E);

    const int gb = NB;
    const float invN = 1.0f / (float)N;

    // encoder: hb = bf16(x @ W_enc + b_enc)
    mfma_gemm<32, 1, false><<<gb, 512, 0, stream>>>(
        x, nullptr, nullptr, nullptr, nullptr, 0.f,
        W_enc, b_enc, (unsigned short*)hb, nullptr, nullptr, N);
    pool_x<<<(N + 63) / 64, 256, 0, stream>>>(x, batch, px, N);

    for (int i = 0; i < 4; i++) {
        float* s1a = stats + (i * 2 + 0) * 128;
        float* s1b = s1a + 64;
        float* s2a = stats + (i * 2 + 1) * 128;
        float* s2b = s2a + 64;

        // m = bf16( (t(hb[n]) + sum t(hb[nbr])) @ W1 + b1 ) + stats s1 (fused)
        if (i == 0) {
            gin_gemm1<false><<<gb, 512, 0, stream>>>(
                row, srcs, hb, nullptr, nullptr, nullptr, nullptr, 0.f,
                W1 + (size_t)i * 4096, b1 + i * 64, (unsigned short*)m, s1a, s1b, N);
        } else {
            float* p2a = stats + ((i - 1) * 2 + 1) * 128;
            float* p2b = p2a + 64;
            gin_gemm1<true><<<gb, 512, 0, stream>>>(
                row, srcs, hb, p2a, p2b,
                gout + (i - 1) * 64, bout + (i - 1) * 64, invN,
                W1 + (size_t)i * 4096, b1 + i * 64, (unsigned short*)m, s1a, s1b, N);
        }

        // hb = bf16( relu(bn1(m)) @ W2[i] + b2[i] ) + stats s2
        mfma_gemm<64, 2, true><<<gb, 512, 0, stream>>>(
            m, s1a, s1b, g1 + i * 64, be1 + i * 64, invN,
            W2 + (size_t)i * 4096, b2 + i * 64, (unsigned short*)hb, s2a, s2b, N);

        // pl[i][g] += relu(bn2(hb))
        pool_nodes<<<(N + 31) / 32, 256, 0, stream>>>(
            (const unsigned short*)hb, s2a, s2b, gout + i * 64, bout + i * 64, invN,
            batch, pl + (size_t)i * G * 64, N);
    }

    head_kernel<<<(G * 10 + G + 255) / 256, 256, 0, stream>>>(
        px, pl, fcW0, fcb0, fcW, fcb, y, (float*)d_out, G);
}